// Round 9
// baseline (301.955 us; speedup 1.0000x reference)
//
#include <hip/hip_runtime.h>

#define N_NODES 50000
#define N_EDGES 600000
#define NBLK    196           // (N_NODES+255)/256
#define KDIM    128

typedef short bf16x8 __attribute__((ext_vector_type(8)));
typedef float f32x4  __attribute__((ext_vector_type(4)));
typedef unsigned short u16x8 __attribute__((ext_vector_type(8)));
typedef unsigned short u16x4 __attribute__((ext_vector_type(4)));

// ---------------- bf16 helpers (RNE) ----------------
__device__ inline ushort rne_bf16(float a) {
    union { float f; unsigned u; } v; v.f = a;
    return (ushort)((v.u + 0x7FFFu + ((v.u >> 16) & 1u)) >> 16);
}
__device__ inline float bf16_to_f32(ushort h) {
    return __uint_as_float((unsigned)h << 16);
}
__device__ inline void split_bf16(float a, ushort& hi, ushort& lo) {
    hi = rne_bf16(a);
    float hv = bf16_to_f32(hi);
    lo = rne_bf16(a - hv);
}

// =============== K1: fused count_deg || convert_w || feat->planes ===============
__global__ __launch_bounds__(256) void k_prep(
    const int* __restrict__ dst, int* __restrict__ degi,
    const float* __restrict__ feat,
    ushort* __restrict__ Fhi, ushort* __restrict__ Flo,
    const float* __restrict__ ws0, const float* __restrict__ wn0,
    const float* __restrict__ ws1, const float* __restrict__ wn1,
    const float* __restrict__ ws2, const float* __restrict__ wn2,
    ushort* __restrict__ Bth0, ushort* __restrict__ Btl0,
    ushort* __restrict__ Bth1, ushort* __restrict__ Btl1,
    ushort* __restrict__ Bth2, ushort* __restrict__ Btl2)
{
    const int b = blockIdx.x, t = threadIdx.x;
    if (b < 192) {
        for (int e = b * 256 + t; e < N_EDGES; e += 192 * 256)
            atomicAdd(&degi[dst[e]], 1);
    } else if (b < 256) {
        for (int i = (b - 192) * 256 + t; i < 592 * 128; i += 64 * 256) {
            int bb = i >> 7, k = i & 127;
            const float *Ws, *Wn;
            ushort *H, *L;
            int dout, n;
            if (bb < 256)      { n = bb;       dout = 128; Ws = ws0; Wn = wn0; H = Bth0; L = Btl0; }
            else if (bb < 512) { n = bb - 256; dout = 128; Ws = ws1; Wn = wn1; H = Bth1; L = Btl1; }
            else               { n = bb - 512; dout = 40;  Ws = ws2; Wn = wn2; H = Bth2; L = Btl2; }
            float w = (n < dout) ? Ws[(long)k * dout + n] : Wn[(long)k * dout + (n - dout)];
            ushort hi, lo;
            split_bf16(w, hi, lo);
            H[n * 128 + k] = hi;
            L[n * 128 + k] = lo;
        }
    } else {
        // feat -> hi/lo bf16 planes (16 floats per chunk)
        for (int idx = (b - 256) * 256 + t; idx < N_NODES * 8; idx += 512 * 256) {
            const int row = idx >> 3;
            const int seg = (idx & 7) * 16;
            const float* ap = feat + (long)row * KDIM + seg;
            float f[16];
            #pragma unroll
            for (int q = 0; q < 4; ++q) {
                float4 a = *(const float4*)(ap + q * 4);
                f[q*4+0] = a.x; f[q*4+1] = a.y; f[q*4+2] = a.z; f[q*4+3] = a.w;
            }
            ushort h[16], l[16];
            #pragma unroll
            for (int i = 0; i < 16; ++i) split_bf16(f[i], h[i], l[i]);
            #pragma unroll
            for (int q = 0; q < 2; ++q) {
                uint4 hw, lw;
                hw.x = (unsigned)h[q*8+0] | ((unsigned)h[q*8+1] << 16);
                hw.y = (unsigned)h[q*8+2] | ((unsigned)h[q*8+3] << 16);
                hw.z = (unsigned)h[q*8+4] | ((unsigned)h[q*8+5] << 16);
                hw.w = (unsigned)h[q*8+6] | ((unsigned)h[q*8+7] << 16);
                lw.x = (unsigned)l[q*8+0] | ((unsigned)l[q*8+1] << 16);
                lw.y = (unsigned)l[q*8+2] | ((unsigned)l[q*8+3] << 16);
                lw.z = (unsigned)l[q*8+4] | ((unsigned)l[q*8+5] << 16);
                lw.w = (unsigned)l[q*8+6] | ((unsigned)l[q*8+7] << 16);
                *(uint4*)&Fhi[(long)row * KDIM + seg + q * 8] = hw;
                *(uint4*)&Flo[(long)row * KDIM + seg + q * 8] = lw;
            }
        }
    }
}

// =============== CSR scan kernels ===============
__global__ __launch_bounds__(256) void block_sums_kernel(const int* __restrict__ deg,
                                                         int* __restrict__ bsum, int n) {
    __shared__ int s[256];
    int t = threadIdx.x;
    int i = blockIdx.x * 256 + t;
    s[t] = (i < n) ? deg[i] : 0;
    __syncthreads();
    #pragma unroll
    for (int d = 128; d > 0; d >>= 1) {
        if (t < d) s[t] += s[t + d];
        __syncthreads();
    }
    if (t == 0) bsum[blockIdx.x] = s[0];
}

__global__ __launch_bounds__(256) void scatter_fused_kernel(const int* __restrict__ deg,
                                                            const int* __restrict__ bsum,
                                                            int* __restrict__ off,
                                                            int* __restrict__ cur,
                                                            int n, int nb) {
    __shared__ int s[256];
    int t = threadIdx.x;

    int bv = (t < nb) ? bsum[t] : 0;
    s[t] = bv;
    __syncthreads();
    #pragma unroll
    for (int d = 1; d < 256; d <<= 1) {
        int x = (t >= d) ? s[t - d] : 0;
        __syncthreads();
        s[t] += x;
        __syncthreads();
    }
    int base = (blockIdx.x > 0) ? s[blockIdx.x - 1] : 0;
    if (blockIdx.x == 0 && t == 0) off[n] = s[255];
    __syncthreads();

    int i = blockIdx.x * 256 + t;
    int v = (i < n) ? deg[i] : 0;
    s[t] = v;
    __syncthreads();
    #pragma unroll
    for (int d = 1; d < 256; d <<= 1) {
        int x = (t >= d) ? s[t - d] : 0;
        __syncthreads();
        s[t] += x;
        __syncthreads();
    }
    if (i < n) {
        int excl = s[t] - v + base;
        off[i] = excl;
        cur[i] = excl;
    }
}

// =============== no-LDS plane GEMM cores ===============
// B (weights, split hi/lo) persistent in regs/AGPRs; A fragments loaded
// DIRECTLY from the pre-split planes (16B per load, L1-absorbed 4x wave
// redundancy). No LDS, no barriers -> compiler pipelines across tiles.
// MFMA operands SWAPPED (weight as op-A); triple split product order
// identical to all prior rounds -> bit-identical numerics.

#define WIDE_B_PROLOGUE()                                                                     \
    bf16x8 Bh[4][2], Bl[4][2];                                                                \
    _Pragma("unroll")                                                                         \
    for (int c = 0; c < 4; ++c) {                                                             \
        _Pragma("unroll")                                                                     \
        for (int ct = 0; ct < 2; ++ct) {                                                      \
            const long boff = (long)(colbase + 16 * ct + lane16) * KDIM + c * 32 + quad * 8;  \
            Bh[c][ct] = *(const bf16x8*)(Bth + boff);                                         \
            Bl[c][ct] = *(const bf16x8*)(Btl + boff);                                         \
        }                                                                                     \
    }                                                                                         \
    f32x4 bv[2] = {};                                                                         \
    if (half == 0) {                                                                          \
        _Pragma("unroll")                                                                     \
        for (int ct = 0; ct < 2; ++ct)                                                        \
            bv[ct] = *(const f32x4*)(bias + wave * 32 + 16 * ct + quad * 4);                  \
    }

// one 32-row tile: direct-load A fragments, 48 MFMA, store
#define WIDE_TILE_BODY()                                                                      \
    const int rr0 = rt * 32 + lane16;                                                         \
    const int rr1 = rr0 + 16;                                                                 \
    const long ro0 = (long)((rr0 < M) ? rr0 : (M - 1)) * KDIM + quad * 8;                     \
    const long ro1 = (long)((rr1 < M) ? rr1 : (M - 1)) * KDIM + quad * 8;                     \
    f32x4 acc[2][2] = {};                                                                     \
    _Pragma("unroll")                                                                         \
    for (int c = 0; c < 4; ++c) {                                                             \
        bf16x8 ah0 = *(const bf16x8*)(Phi + ro0 + c * 32);                                    \
        bf16x8 al0 = *(const bf16x8*)(Plo + ro0 + c * 32);                                    \
        bf16x8 ah1 = *(const bf16x8*)(Phi + ro1 + c * 32);                                    \
        bf16x8 al1 = *(const bf16x8*)(Plo + ro1 + c * 32);                                    \
        _Pragma("unroll")                                                                     \
        for (int ct = 0; ct < 2; ++ct) {                                                      \
            acc[0][ct] = __builtin_amdgcn_mfma_f32_16x16x32_bf16(Bh[c][ct], ah0, acc[0][ct], 0, 0, 0); \
            acc[0][ct] = __builtin_amdgcn_mfma_f32_16x16x32_bf16(Bl[c][ct], ah0, acc[0][ct], 0, 0, 0); \
            acc[0][ct] = __builtin_amdgcn_mfma_f32_16x16x32_bf16(Bh[c][ct], al0, acc[0][ct], 0, 0, 0); \
            acc[1][ct] = __builtin_amdgcn_mfma_f32_16x16x32_bf16(Bh[c][ct], ah1, acc[1][ct], 0, 0, 0); \
            acc[1][ct] = __builtin_amdgcn_mfma_f32_16x16x32_bf16(Bl[c][ct], ah1, acc[1][ct], 0, 0, 0); \
            acc[1][ct] = __builtin_amdgcn_mfma_f32_16x16x32_bf16(Bh[c][ct], al1, acc[1][ct], 0, 0, 0); \
        }                                                                                     \
    }                                                                                         \
    _Pragma("unroll")                                                                         \
    for (int ct = 0; ct < 2; ++ct) {                                                          \
        const int colL = wave * 32 + 16 * ct + quad * 4;                                      \
        _Pragma("unroll")                                                                     \
        for (int r = 0; r < 2; ++r) {                                                         \
            const int row = rt * 32 + 16 * r + lane16;                                        \
            if (row < M) {                                                                    \
                if (half == 0) {                                                              \
                    *(f32x4*)(S + (long)row * 128 + colL) = acc[r][ct] + bv[ct];              \
                } else {                                                                      \
                    u16x4 t4;                                                                 \
                    _Pragma("unroll")                                                         \
                    for (int i = 0; i < 4; ++i) t4[i] = rne_bf16(acc[r][ct][i]);              \
                    *(u16x4*)(T + (long)row * 128 + colL) = t4;                               \
                }                                                                             \
            }                                                                                 \
        }                                                                                     \
    }

// ---- L0: plane GEMM + fill_csr riding in blocks [0,128) ----
__global__ __launch_bounds__(256, 4) void k_gemm_wide_pl_fill(
    const ushort* __restrict__ Phi, const ushort* __restrict__ Plo,
    const ushort* __restrict__ Bth, const ushort* __restrict__ Btl,
    const float* __restrict__ bias,
    float* __restrict__ S, ushort* __restrict__ T, int M,
    const int* __restrict__ src, const int* __restrict__ dst,
    int* __restrict__ cur, int* __restrict__ ssrcb)
{
    if (blockIdx.x < 128) {   // fill_csr (hidden under GEMM)
        const int gtid = blockIdx.x * 256 + threadIdx.x;
        for (int e = gtid; e < N_EDGES; e += 128 * 256) {
            int p = atomicAdd(&cur[dst[e]], 1);
            ssrcb[p] = src[e];
        }
        return;
    }

    const int bid = blockIdx.x - 128;             // 0..639
    const int tid = threadIdx.x;
    const int wave = tid >> 6;
    const int lane = tid & 63;
    const int lane16 = lane & 15;
    const int quad = lane >> 4;
    const int half = bid & 1;
    const int colbase = half * 128 + wave * 32;
    const int ntiles = (M + 31) >> 5;

    WIDE_B_PROLOGUE();

    for (int rt = bid >> 1; rt < ntiles; rt += 320) {
        WIDE_TILE_BODY();
    }
}

// ---- L1: plane GEMM ----
__global__ __launch_bounds__(256, 4) void k_gemm_wide_pl(
    const ushort* __restrict__ Phi, const ushort* __restrict__ Plo,
    const ushort* __restrict__ Bth, const ushort* __restrict__ Btl,
    const float* __restrict__ bias,
    float* __restrict__ S, ushort* __restrict__ T, int M)
{
    const int tid = threadIdx.x;
    const int wave = tid >> 6;
    const int lane = tid & 63;
    const int lane16 = lane & 15;
    const int quad = lane >> 4;
    const int half = blockIdx.x & 1;
    const int colbase = half * 128 + wave * 32;
    const int ntiles = (M + 31) >> 5;
    const int bstride = gridDim.x >> 1;

    WIDE_B_PROLOGUE();

    for (int rt = blockIdx.x >> 1; rt < ntiles; rt += bstride) {
        WIDE_TILE_BODY();
    }
}

// ---- L2 narrow: dout=40 dual (80 cols), plane A, no LDS ----
__global__ __launch_bounds__(256, 3) void k_gemm_narrow_pl(
    const ushort* __restrict__ Phi, const ushort* __restrict__ Plo,
    const ushort* __restrict__ Bth, const ushort* __restrict__ Btl,
    const float* __restrict__ bias,
    float* __restrict__ S, ushort* __restrict__ T, int M)
{
    const int tid = threadIdx.x;
    const int wave = tid >> 6;
    const int lane = tid & 63;
    const int lane16 = lane & 15;
    const int quad = lane >> 4;
    const int rtw = wave & 1;        // row-half 0/1
    const int cg = wave >> 1;        // col-group 0/1
    const int ctbase = cg * 3;       // 0 or 3
    const int nct = cg ? 2 : 3;
    const int ntiles = (M + 31) >> 5;

    bf16x8 Bh[4][3], Bl[4][3];
    #pragma unroll
    for (int c = 0; c < 4; ++c) {
        #pragma unroll
        for (int j = 0; j < 3; ++j) {
            if (j < nct) {
                const long boff = (long)(16 * (ctbase + j) + lane16) * KDIM + c * 32 + quad * 8;
                Bh[c][j] = *(const bf16x8*)(Bth + boff);
                Bl[c][j] = *(const bf16x8*)(Btl + boff);
            }
        }
    }

    for (int rt = blockIdx.x; rt < ntiles; rt += gridDim.x) {
        const int rr = rt * 32 + rtw * 16 + lane16;
        const long ro = (long)((rr < M) ? rr : (M - 1)) * KDIM + quad * 8;

        f32x4 acc[3] = {};
        #pragma unroll
        for (int c = 0; c < 4; ++c) {
            bf16x8 ah = *(const bf16x8*)(Phi + ro + c * 32);
            bf16x8 al = *(const bf16x8*)(Plo + ro + c * 32);
            #pragma unroll
            for (int j = 0; j < 3; ++j) {
                if (j < nct) {
                    acc[j] = __builtin_amdgcn_mfma_f32_16x16x32_bf16(Bh[c][j], ah, acc[j], 0, 0, 0);
                    acc[j] = __builtin_amdgcn_mfma_f32_16x16x32_bf16(Bl[c][j], ah, acc[j], 0, 0, 0);
                    acc[j] = __builtin_amdgcn_mfma_f32_16x16x32_bf16(Bh[c][j], al, acc[j], 0, 0, 0);
                }
            }
        }

        const int row = rt * 32 + rtw * 16 + lane16;
        #pragma unroll
        for (int j = 0; j < 3; ++j) {
            if (j < nct && row < M) {
                const int col0 = 16 * (ctbase + j) + quad * 4;
                if (col0 < 40) {
                    f32x4 bvv = *(const f32x4*)(bias + col0);
                    *(f32x4*)(S + (long)row * 40 + col0) = acc[j] + bvv;
                } else {
                    u16x4 t4;
                    #pragma unroll
                    for (int i = 0; i < 4; ++i) t4[i] = rne_bf16(acc[j][i]);
                    *(u16x4*)(T + (long)row * 40 + (col0 - 40)) = t4;
                }
            }
        }
    }
}

// =============== aggregation: wave-per-node, writes pre-split hi/lo planes ===============
__global__ __launch_bounds__(256) void k_agg128_pl(
    const float* __restrict__ S, const ushort* __restrict__ T,
    const int* __restrict__ off, const int* __restrict__ ssrcb,
    ushort* __restrict__ Phi, ushort* __restrict__ Plo, int nnodes)
{
    const int node = (blockIdx.x * 256 + threadIdx.x) >> 6;
    if (node >= nnodes) return;
    const int lane = threadIdx.x & 63;
    const int slot = lane >> 4;
    const int col8 = (lane & 15) * 8;

    const int a = off[node];
    const int b = off[node + 1];

    f32x4 acc0a = {0,0,0,0}, acc0b = {0,0,0,0};
    f32x4 acc1a = {0,0,0,0}, acc1b = {0,0,0,0};

    int i = a;
    for (; i + 8 <= b; i += 8) {
        int s0 = ssrcb[i + slot];
        int s1 = ssrcb[i + 4 + slot];
        u16x8 v0 = *(const u16x8*)(T + (long)s0 * 128 + col8);
        u16x8 v1 = *(const u16x8*)(T + (long)s1 * 128 + col8);
        #pragma unroll
        for (int j = 0; j < 4; ++j) {
            acc0a[j] += bf16_to_f32(v0[j]);
            acc0b[j] += bf16_to_f32(v0[4 + j]);
            acc1a[j] += bf16_to_f32(v1[j]);
            acc1b[j] += bf16_to_f32(v1[4 + j]);
        }
    }
    for (; i < b; i += 4) {
        int e = i + slot;
        if (e < b) {
            int s = ssrcb[e];
            u16x8 v = *(const u16x8*)(T + (long)s * 128 + col8);
            #pragma unroll
            for (int j = 0; j < 4; ++j) {
                acc0a[j] += bf16_to_f32(v[j]);
                acc0b[j] += bf16_to_f32(v[4 + j]);
            }
        }
    }
    f32x4 accA = acc0a + acc1a;
    f32x4 accB = acc0b + acc1b;

    #pragma unroll
    for (int mm = 16; mm <= 32; mm <<= 1) {
        #pragma unroll
        for (int j = 0; j < 4; ++j) {
            accA[j] += __shfl_xor((float)accA[j], mm);
            accB[j] += __shfl_xor((float)accB[j], mm);
        }
    }

    if (slot == 0) {
        int deg = b - a;
        float scale = (deg > 0) ? (1.0f / (float)deg) : 0.f;
        f32x4 sA = *(const f32x4*)(S + (long)node * 128 + col8);
        f32x4 sB = *(const f32x4*)(S + (long)node * 128 + col8 + 4);
        f32x4 rA = sA + accA * scale;
        f32x4 rB = sB + accB * scale;
        #pragma unroll
        for (int j = 0; j < 4; ++j) {
            rA[j] = fmaxf(rA[j], 0.f);   // relu (only L0/L1 use this kernel)
            rB[j] = fmaxf(rB[j], 0.f);
        }
        u16x8 ph, pl;
        #pragma unroll
        for (int j = 0; j < 4; ++j) {
            ushort h, l;
            split_bf16(rA[j], h, l); ph[j] = h; pl[j] = l;
        }
        #pragma unroll
        for (int j = 0; j < 4; ++j) {
            ushort h, l;
            split_bf16(rB[j], h, l); ph[4 + j] = h; pl[4 + j] = l;
        }
        *(u16x8*)(Phi + (long)node * 128 + col8) = ph;
        *(u16x8*)(Plo + (long)node * 128 + col8) = pl;
    }
}

__global__ __launch_bounds__(256) void k_agg40(
    const float* __restrict__ S, const ushort* __restrict__ T,
    const int* __restrict__ off, const int* __restrict__ ssrcb,
    float* __restrict__ out, int nnodes)
{
    const int node = (blockIdx.x * 256 + threadIdx.x) >> 6;
    if (node >= nnodes) return;
    const int lane = threadIdx.x & 63;
    const bool active = lane < 60;
    const int slot = active ? (lane / 10) : 5;
    const int fi = lane % 10;
    const int fo = fi * 4;

    const int a = off[node];
    const int b = off[node + 1];

    f32x4 acc0 = {0,0,0,0}, acc1 = {0,0,0,0};

    int i = a;
    for (; i + 12 <= b; i += 12) {
        int s0 = ssrcb[i + slot];
        int s1 = ssrcb[i + 6 + slot];
        u16x4 v0 = *(const u16x4*)(T + (long)s0 * 40 + fo);
        u16x4 v1 = *(const u16x4*)(T + (long)s1 * 40 + fo);
        if (active) {
            #pragma unroll
            for (int j = 0; j < 4; ++j) {
                acc0[j] += bf16_to_f32(v0[j]);
                acc1[j] += bf16_to_f32(v1[j]);
            }
        }
    }
    for (; i < b; i += 6) {
        int e = i + slot;
        if (active && e < b) {
            int s = ssrcb[e];
            u16x4 v = *(const u16x4*)(T + (long)s * 40 + fo);
            #pragma unroll
            for (int j = 0; j < 4; ++j) acc0[j] += bf16_to_f32(v[j]);
        }
    }
    f32x4 acc = acc0 + acc1;

    f32x4 tot = acc;
    #pragma unroll
    for (int d = 10; d <= 50; d += 10) {
        int srcl = fi + d;
        #pragma unroll
        for (int j = 0; j < 4; ++j) tot[j] += __shfl((float)acc[j], srcl);
    }

    if (lane < 10) {
        int deg = b - a;
        float scale = (deg > 0) ? (1.0f / (float)deg) : 0.f;
        f32x4 s4 = *(const f32x4*)(S + (long)node * 40 + fo);
        f32x4 r = s4 + tot * scale;
        *(f32x4*)(out + (long)node * 40 + fo) = r;
    }
}

// =============== launch ===============

extern "C" void kernel_launch(void* const* d_in, const int* in_sizes, int n_in,
                              void* d_out, int out_size, void* d_ws, size_t ws_size,
                              hipStream_t stream) {
    const float* feat = (const float*)d_in[0];
    const int*   src  = (const int*)d_in[1];
    const int*   dst  = (const int*)d_in[2];
    const float* ws0  = (const float*)d_in[3];
    const float* wn0  = (const float*)d_in[4];
    const float* b0   = (const float*)d_in[5];
    const float* ws1  = (const float*)d_in[6];
    const float* wn1  = (const float*)d_in[7];
    const float* b1   = (const float*)d_in[8];
    const float* ws2  = (const float*)d_in[9];
    const float* wn2  = (const float*)d_in[10];
    const float* b2   = (const float*)d_in[11];

    const int N = N_NODES;

    char* ws = (char*)d_ws;
    int*    offsets = (int*)(ws + 0);
    int*    cursor  = (int*)(ws + 200704);
    int*    degi    = (int*)(ws + 401408);
    int*    bsum    = (int*)(ws + 601600);
    int*    ssrcb   = (int*)(ws + 603648);
    ushort* Phi  = (ushort*)(ws + 3003904);   // 12.8 MB — feat planes first, then agg planes
    ushort* Plo  = (ushort*)(ws + 15803904);  // 12.8 MB
    float*  sbuf = (float*)(ws + 28603904);   // 25.6 MB fp32
    ushort* tbuf = (ushort*)(ws + 54203904);  // 12.8 MB bf16

    // B buffers live in d_out scratch (dead before agg40's final write)
    ushort* Ball = (ushort*)d_out;
    ushort* Bth0 = Ball;             // 256 cols x 128: 32768 ushorts
    ushort* Btl0 = Ball + 32768;
    ushort* Bth1 = Ball + 65536;
    ushort* Btl1 = Ball + 98304;
    ushort* Bth2 = Ball + 131072;    // 80 cols x 128
    ushort* Btl2 = Ball + 141312;

    // ---- K0/K1: zero deg; count_deg || convert_w || feat->planes ----
    hipMemsetAsync(degi, 0, (size_t)N * sizeof(int), stream);
    k_prep<<<768, 256, 0, stream>>>(dst, degi, feat, Phi, Plo,
                                    ws0, wn0, ws1, wn1, ws2, wn2,
                                    Bth0, Btl0, Bth1, Btl1, Bth2, Btl2);

    // ---- K2/K3: CSR offsets ----
    block_sums_kernel<<<NBLK, 256, 0, stream>>>(degi, bsum, N);
    scatter_fused_kernel<<<NBLK, 256, 0, stream>>>(degi, bsum, offsets, cursor, N, NBLK);

    const int ga = (N + 3) / 4;   // 12500 agg blocks

    // ---- layer 0: plane GEMM (feat planes) with fill_csr riding in blocks [0,128) ----
    k_gemm_wide_pl_fill<<<768, 256, 0, stream>>>(Phi, Plo, Bth0, Btl0, b0, sbuf, tbuf, N,
                                                 src, dst, cursor, ssrcb);
    k_agg128_pl<<<ga, 256, 0, stream>>>(sbuf, tbuf, offsets, ssrcb, Phi, Plo, N);

    // ---- layer 1: plane GEMM ----
    k_gemm_wide_pl<<<768, 256, 0, stream>>>(Phi, Plo, Bth1, Btl1, b1, sbuf, tbuf, N);
    k_agg128_pl<<<ga, 256, 0, stream>>>(sbuf, tbuf, offsets, ssrcb, Phi, Plo, N);

    // ---- layer 2: narrow plane GEMM, agg writes final output ----
    k_gemm_narrow_pl<<<512, 256, 0, stream>>>(Phi, Plo, Bth2, Btl2, b2, sbuf, tbuf, N);
    k_agg40<<<ga, 256, 0, stream>>>(sbuf, tbuf, offsets, ssrcb, (float*)d_out, N);
}